// Round 1
// baseline (75.622 us; speedup 1.0000x reference)
//
#include <hip/hip_runtime.h>
#include <math.h>

// SurrogateCanny fused kernel.
// out[p] = 1.0f iff  gm[p] > gm[p+off_d] && gm[p] > gm[p-off_d] && gm[p] - thr > 0
// where gm = sqrt(gx^2+gy^2) (Sobel-ish, img zero-padded),
//       gm zero-padded outside image for the NMS neighbor reads,
//       d = round((atanf(gy/gx)*(360/pi) + 180)/45) & 3,
//       off_d in {(0,1),(-1,1),(-1,0),(-1,-1)}.

constexpr int W = 1024, H = 1024;
constexpr int TX = 128, TY = 8;      // output tile per block (256 threads)
constexpr int IW = TX + 4, IH = TY + 4;  // img tile with halo 2
constexpr int GW = TX + 2, GH = TY + 2;  // gm tile with halo 1

__device__ __forceinline__ void sobel_pair(float a00, float a01, float a02,
                                           float a10, float a12,
                                           float a20, float a21, float a22,
                                           float& gxv, float& gyv) {
  // row-major accumulation order, no FMA contraction (pragma in caller scope)
  gxv = ((((-0.5f * a00 + 0.5f * a02) + -1.0f * a10) + 1.0f * a12) + -0.5f * a20) + 0.5f * a22;
  gyv = ((((-0.5f * a00 + -1.0f * a01) + -0.5f * a02) + 0.5f * a20) + 1.0f * a21) + 0.5f * a22;
}

__global__ __launch_bounds__(256)
void canny_kernel(const float* __restrict__ img, const float* __restrict__ thrp,
                  float* __restrict__ out) {
#pragma clang fp contract(off)
  __shared__ float s_img[IH][IW];
  __shared__ float s_gm[GH][GW];

  const int b   = blockIdx.z;
  const int bx0 = blockIdx.x * TX;
  const int by0 = blockIdx.y * TY;
  const float* im = img + (size_t)b * (W * H);
  float* ob       = out + (size_t)b * (W * H);
  const int tid = threadIdx.x;

  // Stage img tile [by0-2 .. by0+TY+1] x [bx0-2 .. bx0+TX+1], zero outside image.
  for (int i = tid; i < IH * IW; i += 256) {
    int iy = i / IW, ix = i - iy * IW;
    int gy = by0 + iy - 2, gx = bx0 + ix - 2;
    float v = 0.0f;
    if ((unsigned)gy < (unsigned)H && (unsigned)gx < (unsigned)W) v = im[gy * W + gx];
    s_img[iy][ix] = v;
  }
  __syncthreads();

  // Compute gm tile rows by0-1 .. by0+TY, cols bx0-1 .. bx0+TX; 0 outside image
  // (matches SAME zero-padding of the directional conv over grad_mag).
  for (int i = tid; i < GH * GW; i += 256) {
    int iy = i / GW, ix = i - iy * GW;
    int gy = by0 + iy - 1, gx = bx0 + ix - 1;
    float v = 0.0f;
    if ((unsigned)gy < (unsigned)H && (unsigned)gx < (unsigned)W) {
      float gxv, gyv;
      sobel_pair(s_img[iy][ix],     s_img[iy][ix + 1],     s_img[iy][ix + 2],
                 s_img[iy + 1][ix],                        s_img[iy + 1][ix + 2],
                 s_img[iy + 2][ix], s_img[iy + 2][ix + 1], s_img[iy + 2][ix + 2],
                 gxv, gyv);
      v = sqrtf(gxv * gxv + gyv * gyv);
    }
    s_gm[iy][ix] = v;
  }
  __syncthreads();

  const float thr = *thrp;
  const float C = (float)(360.0 / M_PI);  // same f32 constant JAX uses
  const int tx  = tid & (TX - 1);
  const int ty0 = tid >> 7;  // 0..1 (256 threads / 128 cols)

  for (int rr = 0; rr < TY / 2; ++rr) {
    const int ry = ty0 + rr * 2;
    const int gy = by0 + ry, gx = bx0 + tx;

    const float gmc = s_gm[ry + 1][tx + 1];

    // center pixel (gy,gx) -> img tile (ry+2, tx+2); 3x3 window from (ry+1, tx+1)
    float gxv, gyv;
    sobel_pair(s_img[ry + 1][tx + 1], s_img[ry + 1][tx + 2], s_img[ry + 1][tx + 3],
               s_img[ry + 2][tx + 1],                        s_img[ry + 2][tx + 3],
               s_img[ry + 3][tx + 1], s_img[ry + 3][tx + 2], s_img[ry + 3][tx + 3],
               gxv, gyv);

    // orientation bin, replicating the exact f32 op sequence of the reference
    float r  = gyv / gxv;            // IEEE f32 division (+-inf / NaN fine)
    float t  = atanf(r);             // atanf(+-inf) = +-pi/2
    float u  = t * C;
    float v2 = u + 180.0f;
    float w  = v2 / 45.0f;           // in (—eps, 8+eps)
    int   k  = (int)rintf(w);        // round half-to-even, like jnp.round; NaN -> 0
    int   d  = k & 3;                // == clip(int((k%8)%4),0,3) for k in {0..8}

    // offsets[d]: 0:(0,1) 1:(-1,1) 2:(-1,0) 3:(-1,-1)
    int dy = (d == 0) ? 0 : -1;
    int dx = (d == 3) ? -1 : ((d == 2) ? 0 : 1);

    float n1 = s_gm[ry + 1 + dy][tx + 1 + dx];
    float n2 = s_gm[ry + 1 - dy][tx + 1 - dx];

    // keep = min(gmc-n1, gmc-n2) > 0 ; survive threshold: gmc - thr > 0
    bool keep = (gmc - n1 > 0.0f) && (gmc - n2 > 0.0f);
    float ov = (keep && (gmc - thr > 0.0f)) ? 1.0f : 0.0f;

    ob[gy * W + gx] = ov;
  }
}

extern "C" void kernel_launch(void* const* d_in, const int* in_sizes, int n_in,
                              void* d_out, int out_size, void* d_ws, size_t ws_size,
                              hipStream_t stream) {
  const float* img = (const float*)d_in[0];
  const float* thr = (const float*)d_in[4];
  float* out = (float*)d_out;
  const int batch = in_sizes[0] / (W * H);

  dim3 grid(W / TX, H / TY, batch);
  canny_kernel<<<grid, dim3(256), 0, stream>>>(img, thr, out);
}

// Round 3
// 74.670 us; speedup vs baseline: 1.0128x; 1.0128x over previous
//
#include <hip/hip_runtime.h>
#include <math.h>

// SurrogateCanny fused kernel, round 2 (fixes R1 column off-by-one in gm phase).
// out = 1.0 iff gm > both directional neighbors (per orientation bin) and gm > thr.
// Orientation bin via comparison network against tan((2k+1)pi/16); pixels within
// a conservative margin of a boundary use the exact reference pipeline
// (div -> atanf -> *C -> +180 -> /45 -> rint), bit-identical to round 0 (passed).

constexpr int W = 1024, H = 1024;
constexpr int TX = 128, TY = 8;          // output tile per block (256 threads)
constexpr int IH = 12, IW2 = 136;        // img tile: rows by0-2..by0+9, cols bx0-4..bx0+131
constexpr int GH = 10, GSTR = 132;       // gm plane: rows r=-1..8 (a=r+1), cols p=c+1 (c=-1..128)

__device__ __forceinline__ void sobel_pair(float a00, float a01, float a02,
                                           float a10, float a12,
                                           float a20, float a21, float a22,
                                           float& gxv, float& gyv) {
  // row-major accumulation order, no FMA contraction (pragma in caller scope)
  gxv = ((((-0.5f * a00 + 0.5f * a02) + -1.0f * a10) + 1.0f * a12) + -0.5f * a20) + 0.5f * a22;
  gyv = ((((-0.5f * a00 + -1.0f * a01) + -0.5f * a02) + 0.5f * a20) + 1.0f * a21) + 0.5f * a22;
}

__global__ __launch_bounds__(256)
void canny_kernel(const float* __restrict__ img, const float* __restrict__ thrp,
                  float* __restrict__ out) {
#pragma clang fp contract(off)
  __shared__ __align__(16) float s_img[IH][IW2];
  __shared__ __align__(16) float s_gm[GH][GSTR];
  __shared__ __align__(16) float s_gxy[TY][TX][2];  // centers only: gx, gy

  const int b   = blockIdx.z;
  const int bx0 = blockIdx.x * TX;
  const int by0 = blockIdx.y * TY;
  const float* im = img + (size_t)b * (W * H);
  float* ob       = out + (size_t)b * (W * H);
  const int tid = threadIdx.x;
  const bool edge = (bx0 == 0) || (bx0 + TX == W) || (by0 == 0) || (by0 + TY == H);

  // ---- Stage img tile: rows by0-2..by0+9, cols bx0-4..bx0+131, zero outside ----
  if (!edge) {
    const float* base = im + (size_t)(by0 - 2) * W + (bx0 - 4);
    {
      int u = tid;                    // 408 float4 units: 12 rows x 34
      int row = u / 34, col = u - row * 34;
      float4 v = *reinterpret_cast<const float4*>(base + row * W + col * 4);
      *reinterpret_cast<float4*>(&s_img[row][col * 4]) = v;
    }
    {
      int u = tid + 256;
      if (u < 408) {
        int row = u / 34, col = u - row * 34;
        float4 v = *reinterpret_cast<const float4*>(base + row * W + col * 4);
        *reinterpret_cast<float4*>(&s_img[row][col * 4]) = v;
      }
    }
  } else {
    for (int i = tid; i < IH * IW2; i += 256) {
      int r = i / IW2, cx = i - r * IW2;
      int gy = by0 - 2 + r, gx = bx0 - 4 + cx;
      float v = 0.0f;
      if ((unsigned)gy < 1024u && (unsigned)gx < 1024u) v = im[gy * W + gx];
      s_img[r][cx] = v;
    }
  }
  __syncthreads();

  // ---- gm (+ gx,gy stash) phase: register-rolling 5-row runs per thread ----
  // gm col c maps to s_img cols c+3..c+5 (image cols bx0+c-1..bx0+c+1).
  {
    const int c  = tid & 127;         // gm col c (image col bx0+c), 0..127
    const int tz = tid >> 7;          // 0..1
    const int rbeg = tz * 5 - 1;      // rows r = rbeg .. rbeg+4  (covers -1..8)
    const int ir = rbeg + 1;          // first img-tile row of the 3-row window

    float x0 = s_img[ir][c + 3],     x1 = s_img[ir][c + 4],     x2 = s_img[ir][c + 5];
    float y0 = s_img[ir + 1][c + 3], y1 = s_img[ir + 1][c + 4], y2 = s_img[ir + 1][c + 5];
#pragma unroll
    for (int q = 0; q < 5; ++q) {
      const int r = rbeg + q;
      float z0 = s_img[ir + 2 + q][c + 3];
      float z1 = s_img[ir + 2 + q][c + 4];
      float z2 = s_img[ir + 2 + q][c + 5];
      float gxv, gyv;
      sobel_pair(x0, x1, x2, y0, y2, z0, z1, z2, gxv, gyv);
      float g = sqrtf(gxv * gxv + gyv * gyv);
      if (edge) {                      // gm is zero outside the image (y only; x in range here)
        if ((unsigned)(by0 + r) >= 1024u) g = 0.0f;
      }
      s_gm[r + 1][c + 1] = g;
      if ((unsigned)r < 8u) { s_gxy[r][c][0] = gxv; s_gxy[r][c][1] = gyv; }
      x0 = y0; x1 = y1; x2 = y2;
      y0 = z0; y1 = z1; y2 = z2;
    }

    // halo cols c=-1 (p=0) and c=128 (p=129): 20 elements
    if (tid < 20) {
      int rr = (tid >> 1) - 1;               // -1..8
      int cc = (tid & 1) ? 128 : -1;
      int irr = rr + 1;
      float gxv, gyv;
      sobel_pair(s_img[irr][cc + 3],     s_img[irr][cc + 4],     s_img[irr][cc + 5],
                 s_img[irr + 1][cc + 3],                         s_img[irr + 1][cc + 5],
                 s_img[irr + 2][cc + 3], s_img[irr + 2][cc + 4], s_img[irr + 2][cc + 5],
                 gxv, gyv);
      float g = sqrtf(gxv * gxv + gyv * gyv);
      if (!((unsigned)(by0 + rr) < 1024u && (unsigned)(bx0 + cc) < 1024u)) g = 0.0f;
      s_gm[rr + 1][cc + 1] = g;
    }
  }
  __syncthreads();

  // ---- pixel phase: 4 consecutive cols per thread, register-resident gm rows ----
  {
    const int ty = tid >> 5;                 // 0..7
    const int c0 = (tid & 31) * 4;           // 0..124
    const float thr = *thrp;

    float4 a4 = *reinterpret_cast<float4*>(&s_gm[ty][c0]);
    float2 a2 = *reinterpret_cast<float2*>(&s_gm[ty][c0 + 4]);
    float4 b4 = *reinterpret_cast<float4*>(&s_gm[ty + 1][c0]);
    float2 b2 = *reinterpret_cast<float2*>(&s_gm[ty + 1][c0 + 4]);
    float4 cc4 = *reinterpret_cast<float4*>(&s_gm[ty + 2][c0]);
    float2 cc2 = *reinterpret_cast<float2*>(&s_gm[ty + 2][c0 + 4]);
    float A[6] = {a4.x, a4.y, a4.z, a4.w, a2.x, a2.y};
    float Bv[6] = {b4.x, b4.y, b4.z, b4.w, b2.x, b2.y};
    float Cv[6] = {cc4.x, cc4.y, cc4.z, cc4.w, cc2.x, cc2.y};

    float4 q0 = *reinterpret_cast<float4*>(&s_gxy[ty][c0][0]);
    float4 q1 = *reinterpret_cast<float4*>(&s_gxy[ty][c0 + 2][0]);
    float gq[8] = {q0.x, q0.y, q0.z, q0.w, q1.x, q1.y, q1.z, q1.w};

    // sector boundaries tan((2k+1)*pi/16) and conservative near-boundary margins
    const float T1 = 0.19891236737965801f, D1 = 5.0e-5f;
    const float T2 = 0.66817863791929898f, D2 = 7.0e-5f;
    const float T3 = 1.49660576266548901f, D3 = 1.5e-4f;
    const float T4 = 5.02733949212584810f, D4 = 1.2e-3f;
    const float C  = (float)(360.0 / M_PI);

    float r4[4];
#pragma unroll
    for (int j = 0; j < 4; ++j) {
      const float gxv = gq[2 * j], gyv = gq[2 * j + 1];
      const float gmc = Bv[j + 1];

      const float av = fabsf(gyv), bv = fabsf(gxv);
      const float c1 = fmaf(-T1, bv, av);
      const float c2 = fmaf(-T2, bv, av);
      const float c3 = fmaf(-T3, bv, av);
      const float c4 = fmaf(-T4, bv, av);
      const bool nearb = (fabsf(c1) < D1 * bv) || (fabsf(c2) < D2 * bv) ||
                         (fabsf(c3) < D3 * bv) || (fabsf(c4) < D4 * bv);
      int d;
      if (nearb) {
        // exact reference pipeline (bit-identical to round 0)
        float r  = gyv / gxv;
        float t  = atanf(r);
        float u  = t * C;
        float v2 = u + 180.0f;
        float w  = v2 / 45.0f;
        int   k  = (int)rintf(w);
        d = k & 3;
      } else {
        const unsigned sgn = (__float_as_uint(gyv) ^ __float_as_uint(gxv)) >> 31;
        if (c1 < 0.0f)      d = 0;
        else if (c2 < 0.0f) d = sgn ? 3 : 1;
        else if (c3 < 0.0f) d = 2;
        else if (c4 < 0.0f) d = sgn ? 1 : 3;
        else                d = 0;
      }

      // offsets: d0:(0,1) d1:(-1,1) d2:(-1,0) d3:(-1,-1); n1 = +off, n2 = -off
      const float n1 = (d == 0) ? Bv[j + 2] : (d == 1) ? A[j + 2] : (d == 2) ? A[j + 1] : A[j];
      const float n2 = (d == 0) ? Bv[j]     : (d == 1) ? Cv[j]    : (d == 2) ? Cv[j + 1] : Cv[j + 2];

      const bool keep = (gmc - n1 > 0.0f) && (gmc - n2 > 0.0f) && (gmc - thr > 0.0f);
      r4[j] = keep ? 1.0f : 0.0f;
    }

    const int gy = by0 + ty;
    *reinterpret_cast<float4*>(ob + (size_t)gy * W + bx0 + c0) =
        make_float4(r4[0], r4[1], r4[2], r4[3]);
  }
}

extern "C" void kernel_launch(void* const* d_in, const int* in_sizes, int n_in,
                              void* d_out, int out_size, void* d_ws, size_t ws_size,
                              hipStream_t stream) {
  const float* img = (const float*)d_in[0];
  const float* thr = (const float*)d_in[4];
  float* out = (float*)d_out;
  const int batch = in_sizes[0] / (W * H);

  dim3 grid(W / TX, H / TY, batch);
  canny_kernel<<<grid, dim3(256), 0, stream>>>(img, thr, out);
}

// Round 5
// 64.491 us; speedup vs baseline: 1.1726x; 1.1578x over previous
//
#include <hip/hip_runtime.h>
#include <math.h>

// SurrogateCanny fused kernel, round 4 (= round 3 resubmitted; infra failure).
// R2 passed bit-exact but spilled the pixel-phase arrays to scratch
// (VGPR=16, +160MB scratch writes). This round: identical math, but the
// pixel phase is manually unrolled with named scalars only — no arrays.

constexpr int W = 1024, H = 1024;
constexpr int TX = 128, TY = 8;          // output tile per block (256 threads)
constexpr int IH = 12, IW2 = 136;        // img tile: rows by0-2..by0+9, cols bx0-4..bx0+131
constexpr int GH = 10, GSTR = 132;       // gm plane: rows r=-1..8 (a=r+1), cols p=c+1 (c=-1..128)

__device__ __forceinline__ void sobel_pair(float a00, float a01, float a02,
                                           float a10, float a12,
                                           float a20, float a21, float a22,
                                           float& gxv, float& gyv) {
  // row-major accumulation order, no FMA contraction (pragma in caller scope)
  gxv = ((((-0.5f * a00 + 0.5f * a02) + -1.0f * a10) + 1.0f * a12) + -0.5f * a20) + 0.5f * a22;
  gyv = ((((-0.5f * a00 + -1.0f * a01) + -0.5f * a02) + 0.5f * a20) + 1.0f * a21) + 0.5f * a22;
}

// Decide one pixel. Named neighbor args:
//   d0: n1=bp2 n2=bm ; d1: n1=ap2 n2=cp0 ; d2: n1=ap1 n2=cp1 ; d3: n1=ap0 n2=cp2
__device__ __forceinline__ float decide(float gxv, float gyv, float gmc,
                                        float bp2, float bm,
                                        float ap0, float ap1, float ap2,
                                        float cp0, float cp1, float cp2,
                                        float thr) {
#pragma clang fp contract(off)
  const float T1 = 0.19891236737965801f, D1 = 5.0e-5f;
  const float T2 = 0.66817863791929898f, D2 = 7.0e-5f;
  const float T3 = 1.49660576266548901f, D3 = 1.5e-4f;
  const float T4 = 5.02733949212584810f, D4 = 1.2e-3f;
  const float C  = (float)(360.0 / M_PI);

  const float av = fabsf(gyv), bv = fabsf(gxv);
  const float c1 = fmaf(-T1, bv, av);
  const float c2 = fmaf(-T2, bv, av);
  const float c3 = fmaf(-T3, bv, av);
  const float c4 = fmaf(-T4, bv, av);
  const bool nearb = (fabsf(c1) < D1 * bv) || (fabsf(c2) < D2 * bv) ||
                     (fabsf(c3) < D3 * bv) || (fabsf(c4) < D4 * bv);
  int d;
  if (nearb) {
    // exact reference pipeline (bit-identical to round 0, which passed)
    float r  = gyv / gxv;
    float t  = atanf(r);
    float u  = t * C;
    float v2 = u + 180.0f;
    float w  = v2 / 45.0f;
    int   k  = (int)rintf(w);
    d = k & 3;
  } else {
    const unsigned sgn = (__float_as_uint(gyv) ^ __float_as_uint(gxv)) >> 31;
    if (c1 < 0.0f)      d = 0;
    else if (c2 < 0.0f) d = sgn ? 3 : 1;
    else if (c3 < 0.0f) d = 2;
    else if (c4 < 0.0f) d = sgn ? 1 : 3;
    else                d = 0;
  }

  const float n1 = (d == 0) ? bp2 : (d == 1) ? ap2 : (d == 2) ? ap1 : ap0;
  const float n2 = (d == 0) ? bm  : (d == 1) ? cp0 : (d == 2) ? cp1 : cp2;

  const bool keep = (gmc - n1 > 0.0f) && (gmc - n2 > 0.0f) && (gmc - thr > 0.0f);
  return keep ? 1.0f : 0.0f;
}

__global__ __launch_bounds__(256)
void canny_kernel(const float* __restrict__ img, const float* __restrict__ thrp,
                  float* __restrict__ out) {
#pragma clang fp contract(off)
  __shared__ __align__(16) float s_img[IH][IW2];
  __shared__ __align__(16) float s_gm[GH][GSTR];
  __shared__ __align__(16) float s_gxy[TY][TX][2];  // centers only: gx, gy

  const int b   = blockIdx.z;
  const int bx0 = blockIdx.x * TX;
  const int by0 = blockIdx.y * TY;
  const float* im = img + (size_t)b * (W * H);
  float* ob       = out + (size_t)b * (W * H);
  const int tid = threadIdx.x;
  const bool edge = (bx0 == 0) || (bx0 + TX == W) || (by0 == 0) || (by0 + TY == H);

  // ---- Stage img tile: rows by0-2..by0+9, cols bx0-4..bx0+131, zero outside ----
  if (!edge) {
    const float* base = im + (size_t)(by0 - 2) * W + (bx0 - 4);
    {
      int u = tid;                    // 408 float4 units: 12 rows x 34
      int row = u / 34, col = u - row * 34;
      float4 v = *reinterpret_cast<const float4*>(base + row * W + col * 4);
      *reinterpret_cast<float4*>(&s_img[row][col * 4]) = v;
    }
    {
      int u = tid + 256;
      if (u < 408) {
        int row = u / 34, col = u - row * 34;
        float4 v = *reinterpret_cast<const float4*>(base + row * W + col * 4);
        *reinterpret_cast<float4*>(&s_img[row][col * 4]) = v;
      }
    }
  } else {
    for (int i = tid; i < IH * IW2; i += 256) {
      int r = i / IW2, cx = i - r * IW2;
      int gy = by0 - 2 + r, gx = bx0 - 4 + cx;
      float v = 0.0f;
      if ((unsigned)gy < 1024u && (unsigned)gx < 1024u) v = im[gy * W + gx];
      s_img[r][cx] = v;
    }
  }
  __syncthreads();

  // ---- gm (+ gx,gy stash) phase: register-rolling 5-row runs per thread ----
  // gm col c maps to s_img cols c+3..c+5 (image cols bx0+c-1..bx0+c+1).
  {
    const int c  = tid & 127;         // gm col c (image col bx0+c), 0..127
    const int tz = tid >> 7;          // 0..1
    const int rbeg = tz * 5 - 1;      // rows r = rbeg .. rbeg+4  (covers -1..8)
    const int ir = rbeg + 1;          // first img-tile row of the 3-row window

    float x0 = s_img[ir][c + 3],     x1 = s_img[ir][c + 4],     x2 = s_img[ir][c + 5];
    float y0 = s_img[ir + 1][c + 3], y1 = s_img[ir + 1][c + 4], y2 = s_img[ir + 1][c + 5];
#pragma unroll
    for (int q = 0; q < 5; ++q) {
      const int r = rbeg + q;
      float z0 = s_img[ir + 2 + q][c + 3];
      float z1 = s_img[ir + 2 + q][c + 4];
      float z2 = s_img[ir + 2 + q][c + 5];
      float gxv, gyv;
      sobel_pair(x0, x1, x2, y0, y2, z0, z1, z2, gxv, gyv);
      float g = sqrtf(gxv * gxv + gyv * gyv);
      if (edge) {                      // gm is zero outside the image (y only; x in range here)
        if ((unsigned)(by0 + r) >= 1024u) g = 0.0f;
      }
      s_gm[r + 1][c + 1] = g;
      if ((unsigned)r < 8u) { s_gxy[r][c][0] = gxv; s_gxy[r][c][1] = gyv; }
      x0 = y0; x1 = y1; x2 = y2;
      y0 = z0; y1 = z1; y2 = z2;
    }

    // halo cols c=-1 (p=0) and c=128 (p=129): 20 elements
    if (tid < 20) {
      int rr = (tid >> 1) - 1;               // -1..8
      int cc = (tid & 1) ? 128 : -1;
      int irr = rr + 1;
      float gxv, gyv;
      sobel_pair(s_img[irr][cc + 3],     s_img[irr][cc + 4],     s_img[irr][cc + 5],
                 s_img[irr + 1][cc + 3],                         s_img[irr + 1][cc + 5],
                 s_img[irr + 2][cc + 3], s_img[irr + 2][cc + 4], s_img[irr + 2][cc + 5],
                 gxv, gyv);
      float g = sqrtf(gxv * gxv + gyv * gyv);
      if (!((unsigned)(by0 + rr) < 1024u && (unsigned)(bx0 + cc) < 1024u)) g = 0.0f;
      s_gm[rr + 1][cc + 1] = g;
    }
  }
  __syncthreads();

  // ---- pixel phase: 4 consecutive cols per thread, fully named scalars ----
  {
    const int ty = tid >> 5;                 // 0..7
    const int c0 = (tid & 31) * 4;           // 0..124
    const float thr = *thrp;

    // gm rows: A = row above (ty), B = center row (ty+1), C = row below (ty+2);
    // col p = c0 + i covers pixel cols c0-1 .. c0+4 (p index = col+1).
    const float4 a4  = *reinterpret_cast<float4*>(&s_gm[ty][c0]);
    const float2 a2  = *reinterpret_cast<float2*>(&s_gm[ty][c0 + 4]);
    const float4 b4  = *reinterpret_cast<float4*>(&s_gm[ty + 1][c0]);
    const float2 b2  = *reinterpret_cast<float2*>(&s_gm[ty + 1][c0 + 4]);
    const float4 cx4 = *reinterpret_cast<float4*>(&s_gm[ty + 2][c0]);
    const float2 cx2 = *reinterpret_cast<float2*>(&s_gm[ty + 2][c0 + 4]);
    const float a0 = a4.x,  a1 = a4.y,  a2v = a4.z, a3 = a4.w,  a4v = a2.x,  a5 = a2.y;
    const float b0 = b4.x,  b1 = b4.y,  b2v = b4.z, b3 = b4.w,  b4v = b2.x,  b5 = b2.y;
    const float c0v = cx4.x, c1v = cx4.y, c2v = cx4.z, c3v = cx4.w, c4vv = cx2.x, c5v = cx2.y;

    const float4 q0 = *reinterpret_cast<float4*>(&s_gxy[ty][c0][0]);
    const float4 q1 = *reinterpret_cast<float4*>(&s_gxy[ty][c0 + 2][0]);

    // pixel j: gmc=B[j+1]; d0 n1=B[j+2] n2=B[j]; d1 n1=A[j+2] n2=C[j];
    //          d2 n1=A[j+1] n2=C[j+1]; d3 n1=A[j] n2=C[j+2]
    const float r0 = decide(q0.x, q0.y, b1, b2v, b0, a0, a1, a2v, c0v, c1v, c2v, thr);
    const float r1 = decide(q0.z, q0.w, b2v, b3, b1, a1, a2v, a3, c1v, c2v, c3v, thr);
    const float r2 = decide(q1.x, q1.y, b3, b4v, b2v, a2v, a3, a4v, c2v, c3v, c4vv, thr);
    const float r3 = decide(q1.z, q1.w, b4v, b5, b3, a3, a4v, a5, c3v, c4vv, c5v, thr);

    const int gy = by0 + ty;
    *reinterpret_cast<float4*>(ob + (size_t)gy * W + bx0 + c0) =
        make_float4(r0, r1, r2, r3);
  }
}

extern "C" void kernel_launch(void* const* d_in, const int* in_sizes, int n_in,
                              void* d_out, int out_size, void* d_ws, size_t ws_size,
                              hipStream_t stream) {
  const float* img = (const float*)d_in[0];
  const float* thr = (const float*)d_in[4];
  float* out = (float*)d_out;
  const int batch = in_sizes[0] / (W * H);

  dim3 grid(W / TX, H / TY, batch);
  canny_kernel<<<grid, dim3(256), 0, stream>>>(img, thr, out);
}

// Round 6
// 64.258 us; speedup vs baseline: 1.1768x; 1.0036x over previous
//
#include <hip/hip_runtime.h>
#include <math.h>

// SurrogateCanny fused kernel, round 5.
// R4 passed (64.5us) but LDS bank conflicts doubled (5.39M cycles) due to the
// interleaved s_gxy[ty][c][2] layout (stride-2 writes, stride-32B float4 reads)
// and float2 gm reads. This round: split gx/gy planes (stride-1 writes,
// consecutive-float4 reads) and float4-only gm reads. Math unchanged.

constexpr int W = 1024, H = 1024;
constexpr int TX = 128, TY = 8;          // output tile per block (256 threads)
constexpr int IH = 12, IW2 = 136;        // img tile: rows by0-2..by0+9, cols bx0-4..bx0+131
constexpr int GH = 10, GSTR = 132;       // gm plane: rows r=-1..8 (a=r+1), cols p=c+1 (c=-1..128)

__device__ __forceinline__ void sobel_pair(float a00, float a01, float a02,
                                           float a10, float a12,
                                           float a20, float a21, float a22,
                                           float& gxv, float& gyv) {
  // row-major accumulation order, no FMA contraction (pragma in caller scope)
  gxv = ((((-0.5f * a00 + 0.5f * a02) + -1.0f * a10) + 1.0f * a12) + -0.5f * a20) + 0.5f * a22;
  gyv = ((((-0.5f * a00 + -1.0f * a01) + -0.5f * a02) + 0.5f * a20) + 1.0f * a21) + 0.5f * a22;
}

// Decide one pixel. Named neighbor args:
//   d0: n1=bp2 n2=bm ; d1: n1=ap2 n2=cp0 ; d2: n1=ap1 n2=cp1 ; d3: n1=ap0 n2=cp2
__device__ __forceinline__ float decide(float gxv, float gyv, float gmc,
                                        float bp2, float bm,
                                        float ap0, float ap1, float ap2,
                                        float cp0, float cp1, float cp2,
                                        float thr) {
#pragma clang fp contract(off)
  const float T1 = 0.19891236737965801f, D1 = 5.0e-5f;
  const float T2 = 0.66817863791929898f, D2 = 7.0e-5f;
  const float T3 = 1.49660576266548901f, D3 = 1.5e-4f;
  const float T4 = 5.02733949212584810f, D4 = 1.2e-3f;
  const float C  = (float)(360.0 / M_PI);

  const float av = fabsf(gyv), bv = fabsf(gxv);
  const float c1 = fmaf(-T1, bv, av);
  const float c2 = fmaf(-T2, bv, av);
  const float c3 = fmaf(-T3, bv, av);
  const float c4 = fmaf(-T4, bv, av);
  const bool nearb = (fabsf(c1) < D1 * bv) || (fabsf(c2) < D2 * bv) ||
                     (fabsf(c3) < D3 * bv) || (fabsf(c4) < D4 * bv);
  int d;
  if (nearb) {
    // exact reference pipeline (bit-identical to round 0, which passed)
    float r  = gyv / gxv;
    float t  = atanf(r);
    float u  = t * C;
    float v2 = u + 180.0f;
    float w  = v2 / 45.0f;
    int   k  = (int)rintf(w);
    d = k & 3;
  } else {
    const unsigned sgn = (__float_as_uint(gyv) ^ __float_as_uint(gxv)) >> 31;
    if (c1 < 0.0f)      d = 0;
    else if (c2 < 0.0f) d = sgn ? 3 : 1;
    else if (c3 < 0.0f) d = 2;
    else if (c4 < 0.0f) d = sgn ? 1 : 3;
    else                d = 0;
  }

  const float n1 = (d == 0) ? bp2 : (d == 1) ? ap2 : (d == 2) ? ap1 : ap0;
  const float n2 = (d == 0) ? bm  : (d == 1) ? cp0 : (d == 2) ? cp1 : cp2;

  const bool keep = (gmc - n1 > 0.0f) && (gmc - n2 > 0.0f) && (gmc - thr > 0.0f);
  return keep ? 1.0f : 0.0f;
}

__global__ __launch_bounds__(256)
void canny_kernel(const float* __restrict__ img, const float* __restrict__ thrp,
                  float* __restrict__ out) {
#pragma clang fp contract(off)
  __shared__ __align__(16) float s_img[IH][IW2];
  __shared__ __align__(16) float s_gm[GH][GSTR];
  __shared__ __align__(16) float s_gx[TY][TX];   // centers only
  __shared__ __align__(16) float s_gy[TY][TX];

  const int b   = blockIdx.z;
  const int bx0 = blockIdx.x * TX;
  const int by0 = blockIdx.y * TY;
  const float* im = img + (size_t)b * (W * H);
  float* ob       = out + (size_t)b * (W * H);
  const int tid = threadIdx.x;
  const bool edge = (bx0 == 0) || (bx0 + TX == W) || (by0 == 0) || (by0 + TY == H);

  // ---- Stage img tile: rows by0-2..by0+9, cols bx0-4..bx0+131, zero outside ----
  if (!edge) {
    const float* base = im + (size_t)(by0 - 2) * W + (bx0 - 4);
    {
      int u = tid;                    // 408 float4 units: 12 rows x 34
      int row = u / 34, col = u - row * 34;
      float4 v = *reinterpret_cast<const float4*>(base + row * W + col * 4);
      *reinterpret_cast<float4*>(&s_img[row][col * 4]) = v;
    }
    {
      int u = tid + 256;
      if (u < 408) {
        int row = u / 34, col = u - row * 34;
        float4 v = *reinterpret_cast<const float4*>(base + row * W + col * 4);
        *reinterpret_cast<float4*>(&s_img[row][col * 4]) = v;
      }
    }
  } else {
    for (int i = tid; i < IH * IW2; i += 256) {
      int r = i / IW2, cx = i - r * IW2;
      int gy = by0 - 2 + r, gx = bx0 - 4 + cx;
      float v = 0.0f;
      if ((unsigned)gy < 1024u && (unsigned)gx < 1024u) v = im[gy * W + gx];
      s_img[r][cx] = v;
    }
  }
  __syncthreads();

  // ---- gm (+ gx,gy stash) phase: register-rolling 5-row runs per thread ----
  // gm col c maps to s_img cols c+3..c+5 (image cols bx0+c-1..bx0+c+1).
  {
    const int c  = tid & 127;         // gm col c (image col bx0+c), 0..127
    const int tz = tid >> 7;          // 0..1
    const int rbeg = tz * 5 - 1;      // rows r = rbeg .. rbeg+4  (covers -1..8)
    const int ir = rbeg + 1;          // first img-tile row of the 3-row window

    float x0 = s_img[ir][c + 3],     x1 = s_img[ir][c + 4],     x2 = s_img[ir][c + 5];
    float y0 = s_img[ir + 1][c + 3], y1 = s_img[ir + 1][c + 4], y2 = s_img[ir + 1][c + 5];
#pragma unroll
    for (int q = 0; q < 5; ++q) {
      const int r = rbeg + q;
      float z0 = s_img[ir + 2 + q][c + 3];
      float z1 = s_img[ir + 2 + q][c + 4];
      float z2 = s_img[ir + 2 + q][c + 5];
      float gxv, gyv;
      sobel_pair(x0, x1, x2, y0, y2, z0, z1, z2, gxv, gyv);
      float g = sqrtf(gxv * gxv + gyv * gyv);
      if (edge) {                      // gm is zero outside the image (y only; x in range here)
        if ((unsigned)(by0 + r) >= 1024u) g = 0.0f;
      }
      s_gm[r + 1][c + 1] = g;
      if ((unsigned)r < 8u) { s_gx[r][c] = gxv; s_gy[r][c] = gyv; }
      x0 = y0; x1 = y1; x2 = y2;
      y0 = z0; y1 = z1; y2 = z2;
    }

    // halo cols c=-1 (p=0) and c=128 (p=129): 20 elements
    if (tid < 20) {
      int rr = (tid >> 1) - 1;               // -1..8
      int cc = (tid & 1) ? 128 : -1;
      int irr = rr + 1;
      float gxv, gyv;
      sobel_pair(s_img[irr][cc + 3],     s_img[irr][cc + 4],     s_img[irr][cc + 5],
                 s_img[irr + 1][cc + 3],                         s_img[irr + 1][cc + 5],
                 s_img[irr + 2][cc + 3], s_img[irr + 2][cc + 4], s_img[irr + 2][cc + 5],
                 gxv, gyv);
      float g = sqrtf(gxv * gxv + gyv * gyv);
      if (!((unsigned)(by0 + rr) < 1024u && (unsigned)(bx0 + cc) < 1024u)) g = 0.0f;
      s_gm[rr + 1][cc + 1] = g;
    }
  }
  __syncthreads();

  // ---- pixel phase: 4 consecutive cols per thread, fully named scalars ----
  {
    const int ty = tid >> 5;                 // 0..7
    const int c0 = (tid & 31) * 4;           // 0..124
    const float thr = *thrp;

    // gm rows: A = row above (ty), B = center row (ty+1), C = row below (ty+2);
    // col p = c0 + i covers pixel cols c0-1 .. c0+4 (p index = col+1).
    // All LDS reads are aligned float4 (lane-consecutive, conflict-free).
    const float4 a4  = *reinterpret_cast<float4*>(&s_gm[ty][c0]);
    const float4 a2  = *reinterpret_cast<float4*>(&s_gm[ty][c0 + 4]);
    const float4 b4  = *reinterpret_cast<float4*>(&s_gm[ty + 1][c0]);
    const float4 b2  = *reinterpret_cast<float4*>(&s_gm[ty + 1][c0 + 4]);
    const float4 cx4 = *reinterpret_cast<float4*>(&s_gm[ty + 2][c0]);
    const float4 cx2 = *reinterpret_cast<float4*>(&s_gm[ty + 2][c0 + 4]);
    const float a0 = a4.x,  a1 = a4.y,  a2v = a4.z, a3 = a4.w,  a4v = a2.x,  a5 = a2.y;
    const float b0 = b4.x,  b1 = b4.y,  b2v = b4.z, b3 = b4.w,  b4v = b2.x,  b5 = b2.y;
    const float c0v = cx4.x, c1v = cx4.y, c2v = cx4.z, c3v = cx4.w, c4vv = cx2.x, c5v = cx2.y;

    const float4 gx4 = *reinterpret_cast<float4*>(&s_gx[ty][c0]);
    const float4 gy4 = *reinterpret_cast<float4*>(&s_gy[ty][c0]);

    // pixel j: gmc=B[j+1]; d0 n1=B[j+2] n2=B[j]; d1 n1=A[j+2] n2=C[j];
    //          d2 n1=A[j+1] n2=C[j+1]; d3 n1=A[j] n2=C[j+2]
    const float r0 = decide(gx4.x, gy4.x, b1, b2v, b0, a0, a1, a2v, c0v, c1v, c2v, thr);
    const float r1 = decide(gx4.y, gy4.y, b2v, b3, b1, a1, a2v, a3, c1v, c2v, c3v, thr);
    const float r2 = decide(gx4.z, gy4.z, b3, b4v, b2v, a2v, a3, a4v, c2v, c3v, c4vv, thr);
    const float r3 = decide(gx4.w, gy4.w, b4v, b5, b3, a3, a4v, a5, c3v, c4vv, c5v, thr);

    const int gy = by0 + ty;
    *reinterpret_cast<float4*>(ob + (size_t)gy * W + bx0 + c0) =
        make_float4(r0, r1, r2, r3);
  }
}

extern "C" void kernel_launch(void* const* d_in, const int* in_sizes, int n_in,
                              void* d_out, int out_size, void* d_ws, size_t ws_size,
                              hipStream_t stream) {
  const float* img = (const float*)d_in[0];
  const float* thr = (const float*)d_in[4];
  float* out = (float*)d_out;
  const int batch = in_sizes[0] / (W * H);

  dim3 grid(W / TX, H / TY, batch);
  canny_kernel<<<grid, dim3(256), 0, stream>>>(img, thr, out);
}

// Round 7
// 53.334 us; speedup vs baseline: 1.4179x; 1.2048x over previous
//
#include <hip/hip_runtime.h>
#include <math.h>

// SurrogateCanny fused kernel, round 6.
// Column-ownership restructure: TY=16, each thread owns an 8-row column strip.
// Own-column gm + gx/gy stay in registers across the barrier (no s_gx/s_gy,
// no b128 LDS reads); neighbor columns read as lane-stride-1 b32 (conflict-
// free). All arithmetic (sobel_pair/sqrtf/decide) source-identical to R5.

constexpr int W = 1024, H = 1024;
constexpr int TX = 128, TY = 16;         // output tile per block (256 threads)
constexpr int IH = TY + 4, IW2 = 136;    // img tile: rows by0-2..by0+17, cols bx0-4..bx0+131
constexpr int GH = TY + 2, GSTR = 132;   // gm plane: rows r=-1..16 (idx r+1), cols p=c+1

__device__ __forceinline__ void sobel_pair(float a00, float a01, float a02,
                                           float a10, float a12,
                                           float a20, float a21, float a22,
                                           float& gxv, float& gyv) {
  // row-major accumulation order, no FMA contraction (pragma in caller scope)
  gxv = ((((-0.5f * a00 + 0.5f * a02) + -1.0f * a10) + 1.0f * a12) + -0.5f * a20) + 0.5f * a22;
  gyv = ((((-0.5f * a00 + -1.0f * a01) + -0.5f * a02) + 0.5f * a20) + 1.0f * a21) + 0.5f * a22;
}

// Decide one pixel. Named neighbor args:
//   d0: n1=bp2 n2=bm ; d1: n1=ap2 n2=cp0 ; d2: n1=ap1 n2=cp1 ; d3: n1=ap0 n2=cp2
__device__ __forceinline__ float decide(float gxv, float gyv, float gmc,
                                        float bp2, float bm,
                                        float ap0, float ap1, float ap2,
                                        float cp0, float cp1, float cp2,
                                        float thr) {
#pragma clang fp contract(off)
  const float T1 = 0.19891236737965801f, D1 = 5.0e-5f;
  const float T2 = 0.66817863791929898f, D2 = 7.0e-5f;
  const float T3 = 1.49660576266548901f, D3 = 1.5e-4f;
  const float T4 = 5.02733949212584810f, D4 = 1.2e-3f;
  const float C  = (float)(360.0 / M_PI);

  const float av = fabsf(gyv), bv = fabsf(gxv);
  const float c1 = fmaf(-T1, bv, av);
  const float c2 = fmaf(-T2, bv, av);
  const float c3 = fmaf(-T3, bv, av);
  const float c4 = fmaf(-T4, bv, av);
  const bool nearb = (fabsf(c1) < D1 * bv) || (fabsf(c2) < D2 * bv) ||
                     (fabsf(c3) < D3 * bv) || (fabsf(c4) < D4 * bv);
  int d;
  if (nearb) {
    // exact reference pipeline (bit-identical to round 0, which passed)
    float r  = gyv / gxv;
    float t  = atanf(r);
    float u  = t * C;
    float v2 = u + 180.0f;
    float w  = v2 / 45.0f;
    int   k  = (int)rintf(w);
    d = k & 3;
  } else {
    const unsigned sgn = (__float_as_uint(gyv) ^ __float_as_uint(gxv)) >> 31;
    if (c1 < 0.0f)      d = 0;
    else if (c2 < 0.0f) d = sgn ? 3 : 1;
    else if (c3 < 0.0f) d = 2;
    else if (c4 < 0.0f) d = sgn ? 1 : 3;
    else                d = 0;
  }

  const float n1 = (d == 0) ? bp2 : (d == 1) ? ap2 : (d == 2) ? ap1 : ap0;
  const float n2 = (d == 0) ? bm  : (d == 1) ? cp0 : (d == 2) ? cp1 : cp2;

  const bool keep = (gmc - n1 > 0.0f) && (gmc - n2 > 0.0f) && (gmc - thr > 0.0f);
  return keep ? 1.0f : 0.0f;
}

__global__ __launch_bounds__(256)
void canny_kernel(const float* __restrict__ img, const float* __restrict__ thrp,
                  float* __restrict__ out) {
#pragma clang fp contract(off)
  __shared__ __align__(16) float s_img[IH][IW2];
  __shared__ __align__(16) float s_gm[GH][GSTR];

  const int b   = blockIdx.z;
  const int bx0 = blockIdx.x * TX;
  const int by0 = blockIdx.y * TY;
  const float* im = img + (size_t)b * (W * H);
  float* ob       = out + (size_t)b * (W * H);
  const int tid = threadIdx.x;
  const bool edge = (bx0 == 0) || (bx0 + TX == W) || (by0 == 0) || (by0 + TY == H);

  // ---- Stage img tile: rows by0-2..by0+17, cols bx0-4..bx0+131, zero outside ----
  // 20 rows x 34 float4 = 680 units; row stride 136 floats = 34 float4, so the
  // LDS address is simply u*16 bytes (fully linear).
  if (!edge) {
    const float* base = im + (size_t)(by0 - 2) * W + (bx0 - 4);
    {
      int u = tid;
      int row = u / 34, col = u - row * 34;
      *reinterpret_cast<float4*>(&s_img[0][0] + u * 4) =
          *reinterpret_cast<const float4*>(base + row * W + col * 4);
    }
    {
      int u = tid + 256;
      int row = u / 34, col = u - row * 34;
      *reinterpret_cast<float4*>(&s_img[0][0] + u * 4) =
          *reinterpret_cast<const float4*>(base + row * W + col * 4);
    }
    {
      int u = tid + 512;
      if (u < 680) {
        int row = u / 34, col = u - row * 34;
        *reinterpret_cast<float4*>(&s_img[0][0] + u * 4) =
            *reinterpret_cast<const float4*>(base + row * W + col * 4);
      }
    }
  } else {
    for (int i = tid; i < IH * IW2; i += 256) {
      int r = i / IW2, cx = i - r * IW2;
      int gy = by0 - 2 + r, gx = bx0 - 4 + cx;
      float v = 0.0f;
      if ((unsigned)gy < 1024u && (unsigned)gx < 1024u) v = im[gy * W + gx];
      s_img[r][cx] = v;
    }
  }
  __syncthreads();

  const int c  = tid & 127;           // owned column (image col bx0+c)
  const int tz = tid >> 7;            // strip: pixel rows 8*tz .. 8*tz+7

  // ---- gm phase: 10 rows per thread, rows r = 8*tz-1 .. 8*tz+8 ----
  // Window tile rows for step Q: tr0+Q .. tr0+Q+2 with tr0 = 8*tz; gm col c
  // uses s_img cols c+3..c+5. Rows 7,8 are computed by both strips from the
  // same LDS data -> identical bits -> benign duplicate write.
  float gq0, gq1, gq2, gq3, gq4, gq5, gq6, gq7, gq8, gq9;
  float gx0, gx1, gx2, gx3, gx4, gx5, gx6, gx7;
  float gy0, gy1, gy2, gy3, gy4, gy5, gy6, gy7;
  {
    const int tr0 = 8 * tz;
    const int rowbase = by0 + tr0 - 1;     // image row at Q=0
    float x0 = s_img[tr0][c + 3],     x1 = s_img[tr0][c + 4],     x2 = s_img[tr0][c + 5];
    float y0 = s_img[tr0 + 1][c + 3], y1 = s_img[tr0 + 1][c + 4], y2 = s_img[tr0 + 1][c + 5];

#define GM_STEP(Q, GQ, SAVE)                                                   \
    {                                                                          \
      float z0 = s_img[tr0 + Q + 2][c + 3];                                    \
      float z1 = s_img[tr0 + Q + 2][c + 4];                                    \
      float z2 = s_img[tr0 + Q + 2][c + 5];                                    \
      float gxv, gyv;                                                          \
      sobel_pair(x0, x1, x2, y0, y2, z0, z1, z2, gxv, gyv);                    \
      float g = sqrtf(gxv * gxv + gyv * gyv);                                  \
      if (edge) { if ((unsigned)(rowbase + Q) >= 1024u) g = 0.0f; }            \
      s_gm[tr0 + Q][c + 1] = g;                                                \
      GQ = g;                                                                  \
      SAVE;                                                                    \
      x0 = y0; x1 = y1; x2 = y2;                                               \
      y0 = z0; y1 = z1; y2 = z2;                                               \
    }

    GM_STEP(0, gq0, (void)0)
    GM_STEP(1, gq1, ((gx0 = gxv), (gy0 = gyv)))
    GM_STEP(2, gq2, ((gx1 = gxv), (gy1 = gyv)))
    GM_STEP(3, gq3, ((gx2 = gxv), (gy2 = gyv)))
    GM_STEP(4, gq4, ((gx3 = gxv), (gy3 = gyv)))
    GM_STEP(5, gq5, ((gx4 = gxv), (gy4 = gyv)))
    GM_STEP(6, gq6, ((gx5 = gxv), (gy5 = gyv)))
    GM_STEP(7, gq7, ((gx6 = gxv), (gy6 = gyv)))
    GM_STEP(8, gq8, ((gx7 = gxv), (gy7 = gyv)))
    GM_STEP(9, gq9, (void)0)
#undef GM_STEP
  }

  // halo cols c=-1 (p=0) and c=128 (p=129): rows r=-1..16 -> 36 elements
  if (tid < 36) {
    int rr = tid >> 1;                     // 0..17, gm row r = rr-1
    int r  = rr - 1;
    int cc = (tid & 1) ? 128 : -1;
    float gxv, gyv;
    sobel_pair(s_img[rr][cc + 3],     s_img[rr][cc + 4],     s_img[rr][cc + 5],
               s_img[rr + 1][cc + 3],                        s_img[rr + 1][cc + 5],
               s_img[rr + 2][cc + 3], s_img[rr + 2][cc + 4], s_img[rr + 2][cc + 5],
               gxv, gyv);
    float g = sqrtf(gxv * gxv + gyv * gyv);
    if (!((unsigned)(by0 + r) < 1024u && (unsigned)(bx0 + cc) < 1024u)) g = 0.0f;
    s_gm[rr][cc + 1] = g;
  }
  __syncthreads();

  // ---- pixel phase: 8-pixel column per thread ----
  // L_k / R_k = gm of cols c-1 / c+1 at gm row 8*tz-1+k  (s_gm idx 8*tz+k).
  {
    const float thr = *thrp;
    const int gb = 8 * tz;
    const float L0 = s_gm[gb + 0][c], R0 = s_gm[gb + 0][c + 2];
    const float L1 = s_gm[gb + 1][c], R1 = s_gm[gb + 1][c + 2];
    const float L2 = s_gm[gb + 2][c], R2 = s_gm[gb + 2][c + 2];
    const float L3 = s_gm[gb + 3][c], R3 = s_gm[gb + 3][c + 2];
    const float L4 = s_gm[gb + 4][c], R4 = s_gm[gb + 4][c + 2];
    const float L5 = s_gm[gb + 5][c], R5 = s_gm[gb + 5][c + 2];
    const float L6 = s_gm[gb + 6][c], R6 = s_gm[gb + 6][c + 2];
    const float L7 = s_gm[gb + 7][c], R7 = s_gm[gb + 7][c + 2];
    const float L8 = s_gm[gb + 8][c], R8 = s_gm[gb + 8][c + 2];
    const float L9 = s_gm[gb + 9][c], R9 = s_gm[gb + 9][c + 2];

    float* orow = ob + (size_t)(by0 + gb) * W + bx0 + c;

    // pixel j: gmc=gq[j+1]; d0 n1=R[j+1] n2=L[j+1]; d1 n1=R[j] n2=L[j+2];
    //          d2 n1=gq[j] n2=gq[j+2];  d3 n1=L[j] n2=R[j+2]
    orow[0 * W] = decide(gx0, gy0, gq1, R1, L1, L0, gq0, R0, L2, gq2, R2, thr);
    orow[1 * W] = decide(gx1, gy1, gq2, R2, L2, L1, gq1, R1, L3, gq3, R3, thr);
    orow[2 * W] = decide(gx2, gy2, gq3, R3, L3, L2, gq2, R2, L4, gq4, R4, thr);
    orow[3 * W] = decide(gx3, gy3, gq4, R4, L4, L3, gq3, R3, L5, gq5, R5, thr);
    orow[4 * W] = decide(gx4, gy4, gq5, R5, L5, L4, gq4, R4, L6, gq6, R6, thr);
    orow[5 * W] = decide(gx5, gy5, gq6, R6, L6, L5, gq5, R5, L7, gq7, R7, thr);
    orow[6 * W] = decide(gx6, gy6, gq7, R7, L7, L6, gq6, R6, L8, gq8, R8, thr);
    orow[7 * W] = decide(gx7, gy7, gq8, R8, L8, L7, gq7, R7, L9, gq9, R9, thr);
  }
}

extern "C" void kernel_launch(void* const* d_in, const int* in_sizes, int n_in,
                              void* d_out, int out_size, void* d_ws, size_t ws_size,
                              hipStream_t stream) {
  const float* img = (const float*)d_in[0];
  const float* thr = (const float*)d_in[4];
  float* out = (float*)d_out;
  const int batch = in_sizes[0] / (W * H);

  dim3 grid(W / TX, H / TY, batch);
  canny_kernel<<<grid, dim3(256), 0, stream>>>(img, thr, out);
}